// Round 1
// baseline (1229.636 us; speedup 1.0000x reference)
//
#include <hip/hip_runtime.h>
#include <math.h>

#define B_ 16
#define N_ 512
#define D_ 32
#define E_ 8176
#define SLEFT_ 16384
#define FSS_ 601
#define BN_ (B_*N_)            // 8192
#define BE_ (B_*E_)            // 130816
#define NSROW_ (SLEFT_ + 2*E_) // 32736
#define OUT_R_ (B_*FSS_)       // 9616

// ---------------- index / CSR build ----------------

__global__ __launch_bounds__(256) void k_indices(const float* __restrict__ ns,
                                                 int* __restrict__ src_i,
                                                 int* __restrict__ dst_i,
                                                 int* __restrict__ cnt) {
  int idx = blockIdx.x*256 + threadIdx.x;
  if (idx >= BE_) return;
  int b = idx / E_;
  int j = idx - b*E_;
  const float* row = ns + (size_t)b*NSROW_;
  int s = (int)row[SLEFT_ + j];
  int r = (int)row[SLEFT_ + E_ + j];
  src_i[idx] = b*N_ + s;
  int dst = b*N_ + r;
  dst_i[idx] = dst;
  atomicAdd(&cnt[dst], 1);
}

__global__ __launch_bounds__(1024) void k_scan(const int* __restrict__ cnt,
                                               int* __restrict__ rowptr) {
  __shared__ int part[1024];
  int t = threadIdx.x;
  int base = t*8;
  int loc[8]; int s = 0;
  #pragma unroll
  for (int i=0;i<8;i++){ loc[i]=cnt[base+i]; s+=loc[i]; }
  part[t]=s; __syncthreads();
  for (int off=1; off<1024; off<<=1) {
    int v = (t>=off)?part[t-off]:0;
    __syncthreads();
    part[t]+=v;
    __syncthreads();
  }
  int ex = (t==0)?0:part[t-1];
  #pragma unroll
  for (int i=0;i<8;i++){ rowptr[base+i]=ex; ex+=loc[i]; }
  if (t==1023) rowptr[BN_]=ex;
}

__global__ __launch_bounds__(256) void k_scatter(const int* __restrict__ src_i,
                                                 const int* __restrict__ dst_i,
                                                 const int* __restrict__ rowptr,
                                                 int* __restrict__ fill,
                                                 int* __restrict__ csr_src) {
  int idx = blockIdx.x*256+threadIdx.x;
  if (idx>=BE_) return;
  int dst = dst_i[idx];
  int pos = rowptr[dst] + atomicAdd(&fill[dst],1);
  csr_src[pos] = src_i[idx];
}

// ---------------- sa = [nodes | one_hot] ----------------

__global__ __launch_bounds__(256) void k_sa(const float* __restrict__ ns,
                                            const int* __restrict__ a,
                                            float* __restrict__ sa) {
  int idx = blockIdx.x*256+threadIdx.x;  // over BN_*33
  if (idx >= BN_*33) return;
  int v = idx/33, c = idx - v*33;
  int b = v >> 9, n = v & 511;
  float val;
  if (c < 32) val = ns[(size_t)b*NSROW_ + n*32 + c];
  else        val = (a[b]==n) ? 1.f : 0.f;
  sa[idx]=val;
}

// ---------------- fp32 SGEMM: C[M,N] = A[M,K] * W[K,N] ----------------
// 64x64 tile, 16x16 threads, 4x4 micro-tile. M assumed multiple of 64.

__global__ __launch_bounds__(256) void k_sgemm(const float* __restrict__ A,
                                               const float* __restrict__ W,
                                               float* __restrict__ C,
                                               int K, int Nn) {
  __shared__ float As[16][66];
  __shared__ float Bs[16][64];
  int tid = threadIdx.x;
  int tx = tid & 15, ty = tid >> 4;
  int colBase = blockIdx.x * 64;
  int rowBase = blockIdx.y * 64;
  float acc[4][4];
  #pragma unroll
  for (int i=0;i<4;i++)
    #pragma unroll
    for (int j=0;j<4;j++) acc[i][j]=0.f;

  for (int k0 = 0; k0 < K; k0 += 16) {
    #pragma unroll
    for (int i = 0; i < 4; i++) {
      int t = tid + i*256;
      int kk = t & 15, m = t >> 4;
      int gk = k0 + kk;
      As[kk][m] = (gk < K) ? A[(size_t)(rowBase+m)*K + gk] : 0.f;
    }
    #pragma unroll
    for (int i = 0; i < 4; i++) {
      int t = tid + i*256;
      int n = t & 63, kk = t >> 6;
      int gk = k0 + kk, gn = colBase + n;
      Bs[kk][n] = (gk < K && gn < Nn) ? W[(size_t)gk*Nn + gn] : 0.f;
    }
    __syncthreads();
    #pragma unroll
    for (int kk = 0; kk < 16; kk++) {
      float av[4], bv[4];
      #pragma unroll
      for (int i=0;i<4;i++) av[i] = As[kk][ty*4+i];
      #pragma unroll
      for (int j=0;j<4;j++) bv[j] = Bs[kk][tx*4+j];
      #pragma unroll
      for (int i=0;i<4;i++)
        #pragma unroll
        for (int j=0;j<4;j++) acc[i][j] += av[i]*bv[j];
    }
    __syncthreads();
  }
  #pragma unroll
  for (int i=0;i<4;i++) {
    int r = rowBase + ty*4 + i;
    #pragma unroll
    for (int j=0;j<4;j++) {
      int c = colBase + tx*4 + j;
      if (c < Nn) C[(size_t)r*Nn + c] = acc[i][j];
    }
  }
}

// ---------------- per-node attention scalars ----------------

__global__ __launch_bounds__(256) void k_esed(const float* __restrict__ h,
                                              const float* __restrict__ asrc,
                                              const float* __restrict__ adst,
                                              float* __restrict__ es,
                                              float* __restrict__ ed, int dout) {
  int wid = threadIdx.x>>6, lane = threadIdx.x&63;
  int v = blockIdx.x*4 + wid;
  const float* hv = h + (size_t)v*dout;
  float s=0.f, d=0.f;
  for (int c=lane;c<dout;c+=64){ float x=hv[c]; s+=x*asrc[c]; d+=x*adst[c]; }
  #pragma unroll
  for (int o=32;o;o>>=1){ s+=__shfl_xor(s,o,64); d+=__shfl_xor(d,o,64); }
  if (lane==0){ es[v]=s; ed[v]=d; }
}

// ---------------- softmax + aggregation (one wave per node) ----------------

__global__ __launch_bounds__(256) void k_aggregate(const float* __restrict__ h,
                                                   const float* __restrict__ es,
                                                   const float* __restrict__ ed,
                                                   const int* __restrict__ rowptr,
                                                   const int* __restrict__ csr_src,
                                                   const float* __restrict__ bias,
                                                   float* __restrict__ out, int dout) {
  int wid = threadIdx.x>>6, lane = threadIdx.x&63;
  int v = blockIdx.x*4 + wid;
  int s0 = rowptr[v], e0 = rowptr[v+1];
  float edv = ed[v];
  // pass 1: max of leaky(e)
  float m = -__builtin_inff();
  for (int j = s0 + lane; j < e0; j += 64) {
    float e = es[csr_src[j]] + edv;
    e = e > 0.f ? e : 0.2f*e;
    m = fmaxf(m, e);
  }
  #pragma unroll
  for (int o=32;o;o>>=1) m = fmaxf(m, __shfl_xor(m,o,64));
  // pass 2: denominator
  float den = 0.f;
  for (int j = s0 + lane; j < e0; j += 64) {
    float e = es[csr_src[j]] + edv;
    e = e > 0.f ? e : 0.2f*e;
    den += __expf(e - m);
  }
  #pragma unroll
  for (int o=32;o;o>>=1) den += __shfl_xor(den,o,64);
  float scale = 1.f/(den + 1e-16f);
  // pass 3: weighted accumulate, lanes own feature columns
  float acc[10];
  #pragma unroll
  for (int k=0;k<10;k++) acc[k]=0.f;
  for (int j = s0; j < e0; ++j) {
    int u = csr_src[j];
    float e = es[u] + edv;
    e = e > 0.f ? e : 0.2f*e;
    float w = __expf(e - m) * scale;
    const float* hu = h + (size_t)u*dout;
    #pragma unroll
    for (int k=0;k<10;k++) {
      int c = lane + (k<<6);
      if (c < dout) acc[k] += w*hu[c];
    }
  }
  float* ov = out + (size_t)v*dout;
  #pragma unroll
  for (int k=0;k<10;k++) {
    int c = lane + (k<<6);
    if (c < dout) ov[c] = acc[k] + bias[c];
  }
}

// ---------------- LayerNorm over node axis + ReLU ----------------

__global__ __launch_bounds__(256) void k_ln_stats(const float* __restrict__ x,
                                                  float* __restrict__ stats, int dout) {
  int b = blockIdx.z; int c0 = blockIdx.x*64; int n0 = blockIdx.y*64;
  int lc = threadIdx.x&63; int r = threadIdx.x>>6;
  int c = c0+lc;
  float s=0.f,q=0.f;
  if (c<dout){
    for (int i=0;i<16;i++){
      int n = n0 + r*16 + i;
      float xv = x[((size_t)(b*N_+n))*dout + c];
      s+=xv; q+=xv*xv;
    }
  }
  __shared__ float S[4][64], Q[4][64];
  S[r][lc]=s; Q[r][lc]=q;
  __syncthreads();
  if (r==0 && c<dout){
    atomicAdd(&stats[(size_t)b*dout+c],        S[0][lc]+S[1][lc]+S[2][lc]+S[3][lc]);
    atomicAdd(&stats[(size_t)(B_+b)*dout+c],   Q[0][lc]+Q[1][lc]+Q[2][lc]+Q[3][lc]);
  }
}

__global__ __launch_bounds__(256) void k_ln_apply(float* __restrict__ x,
                                                  const float* __restrict__ stats,
                                                  const float* __restrict__ sc,
                                                  const float* __restrict__ of, int dout) {
  int idx = blockIdx.x*256+threadIdx.x;
  if (idx >= BN_*dout) return;
  int v = idx/dout, c = idx - v*dout;
  int b = v>>9;
  float mu  = stats[(size_t)b*dout+c] * (1.f/N_);
  float var = stats[(size_t)(B_+b)*dout+c]*(1.f/N_) - mu*mu;
  float y = (x[idx]-mu)*rsqrtf(var+1e-5f)*sc[c]+of[c];
  x[idx] = y>0.f ? y : 0.f;
}

// ---------------- reward: sum over nodes ----------------

__global__ __launch_bounds__(256) void k_rsum(const float* __restrict__ g,
                                              float* __restrict__ out) {
  int b = blockIdx.z; int c0 = blockIdx.x*64; int n0 = blockIdx.y*64;
  int lc = threadIdx.x & 63; int r = threadIdx.x>>6;
  int c = c0+lc;
  float s = 0.f;
  if (c < FSS_) {
    for (int i=0;i<16;i++){
      int n = n0 + r*16 + i;
      s += g[((size_t)(b*N_+n))*FSS_ + c];
    }
  }
  __shared__ float S[4][64];
  S[r][lc]=s; __syncthreads();
  if (r==0 && c<FSS_) {
    atomicAdd(&out[b*FSS_+c], S[0][lc]+S[1][lc]+S[2][lc]+S[3][lc]);
  }
}

// ---------------- ns_new assembly ----------------

__global__ __launch_bounds__(256) void k_output(const float* __restrict__ f,
                                                const float* __restrict__ ns,
                                                float* __restrict__ out) {
  int idx = blockIdx.x*256+threadIdx.x;
  if (idx >= B_*NSROW_) return;
  int b = idx / NSROW_; int j = idx - b*NSROW_;
  float v = (j < SLEFT_) ? f[(size_t)b*SLEFT_ + j] : ns[(size_t)b*NSROW_ + j];
  out[OUT_R_ + idx] = v;
}

// ---------------- host driver ----------------

static void gat_layer(const float* x, int din, int dout,
                      const float* W, const float* as, const float* ad, const float* bias,
                      const float* s, const float* o,
                      float* h, float* g, float* es, float* ed, float* stats,
                      const int* rowptr, const int* csr_src, hipStream_t stream) {
  dim3 gg((dout+63)/64, BN_/64);
  k_sgemm<<<gg, 256, 0, stream>>>(x, W, h, din, dout);
  k_esed<<<BN_/4, 256, 0, stream>>>(h, as, ad, es, ed, dout);
  k_aggregate<<<BN_/4, 256, 0, stream>>>(h, es, ed, rowptr, csr_src, bias, g, dout);
  if (s) {
    hipMemsetAsync(stats, 0, (size_t)2*B_*dout*sizeof(float), stream);
    k_ln_stats<<<dim3((dout+63)/64, 8, 16), 256, 0, stream>>>(g, stats, dout);
    k_ln_apply<<<(BN_*dout+255)/256, 256, 0, stream>>>(g, stats, s, o, dout);
  }
}

extern "C" void kernel_launch(void* const* d_in, const int* in_sizes, int n_in,
                              void* d_out, int out_size, void* d_ws, size_t ws_size,
                              hipStream_t stream) {
  const float* ns = (const float*)d_in[0];
  const int*   a  = (const int*)d_in[1];

  const float *W[4], *As[4], *Ad[4], *Bb[4], *Sc[3], *Of[3];
  const float *rW[4], *rAs[4], *rAd[4], *rBb[4], *rSc[3], *rOf[3];
  int p = 2;
  for (int i=0;i<4;i++){
    W[i]=(const float*)d_in[p++]; As[i]=(const float*)d_in[p++];
    Ad[i]=(const float*)d_in[p++]; Bb[i]=(const float*)d_in[p++];
    if (i<3){ Sc[i]=(const float*)d_in[p++]; Of[i]=(const float*)d_in[p++]; }
  }
  for (int i=0;i<4;i++){
    rW[i]=(const float*)d_in[p++]; rAs[i]=(const float*)d_in[p++];
    rAd[i]=(const float*)d_in[p++]; rBb[i]=(const float*)d_in[p++];
    if (i<3){ rSc[i]=(const float*)d_in[p++]; rOf[i]=(const float*)d_in[p++]; }
  }

  // carve workspace (256B aligned)
  char* w = (char*)d_ws;
  auto carve = [&](size_t bytes)->void* {
    void* r = (void*)w;
    w += (bytes + 255) & ~(size_t)255;
    return r;
  };
  float* bufA  = (float*)carve((size_t)BN_*FSS_*4);
  float* bufB  = (float*)carve((size_t)BN_*FSS_*4);
  float* sa    = (float*)carve((size_t)BN_*33*4);
  float* es    = (float*)carve((size_t)BN_*4);
  float* ed    = (float*)carve((size_t)BN_*4);
  float* stats = (float*)carve((size_t)2*B_*FSS_*4);
  int* src_i   = (int*)carve((size_t)BE_*4);
  int* dst_i   = (int*)carve((size_t)BE_*4);
  int* cnt     = (int*)carve((size_t)BN_*4);
  int* rowptr  = (int*)carve((size_t)(BN_+1)*4);
  int* fill    = (int*)carve((size_t)BN_*4);
  int* csr_src = (int*)carve((size_t)BE_*4);

  float* out = (float*)d_out;

  hipMemsetAsync(cnt,  0, (size_t)BN_*4, stream);
  hipMemsetAsync(fill, 0, (size_t)BN_*4, stream);
  hipMemsetAsync(out,  0, (size_t)OUT_R_*4, stream);

  k_indices<<<(BE_+255)/256, 256, 0, stream>>>(ns, src_i, dst_i, cnt);
  k_scan<<<1, 1024, 0, stream>>>(cnt, rowptr);
  k_scatter<<<(BE_+255)/256, 256, 0, stream>>>(src_i, dst_i, rowptr, fill, csr_src);
  k_sa<<<(BN_*33+255)/256, 256, 0, stream>>>(ns, a, sa);

  // reward head (601 wide)
  gat_layer(sa,   33,  FSS_, rW[0],rAs[0],rAd[0],rBb[0], rSc[0],rOf[0], bufB, bufA, es, ed, stats, rowptr, csr_src, stream);
  gat_layer(bufA, FSS_,FSS_, rW[1],rAs[1],rAd[1],rBb[1], rSc[1],rOf[1], bufB, bufA, es, ed, stats, rowptr, csr_src, stream);
  gat_layer(bufA, FSS_,FSS_, rW[2],rAs[2],rAd[2],rBb[2], rSc[2],rOf[2], bufB, bufA, es, ed, stats, rowptr, csr_src, stream);
  gat_layer(bufA, FSS_,FSS_, rW[3],rAs[3],rAd[3],rBb[3], nullptr,nullptr, bufB, bufA, es, ed, stats, rowptr, csr_src, stream);
  k_rsum<<<dim3((FSS_+63)/64, 8, 16), 256, 0, stream>>>(bufA, out);

  // next-state head
  gat_layer(sa,   33, 128, W[0],As[0],Ad[0],Bb[0], Sc[0],Of[0], bufB, bufA, es, ed, stats, rowptr, csr_src, stream);
  gat_layer(bufA, 128, 64, W[1],As[1],Ad[1],Bb[1], Sc[1],Of[1], bufB, bufA, es, ed, stats, rowptr, csr_src, stream);
  gat_layer(bufA, 64,  64, W[2],As[2],Ad[2],Bb[2], Sc[2],Of[2], bufB, bufA, es, ed, stats, rowptr, csr_src, stream);
  gat_layer(bufA, 64,  32, W[3],As[3],Ad[3],Bb[3], nullptr,nullptr, bufB, bufA, es, ed, stats, rowptr, csr_src, stream);
  k_output<<<(B_*NSROW_+255)/256, 256, 0, stream>>>(bufA, ns, out);
}

// Round 2
// 969.049 us; speedup vs baseline: 1.2689x; 1.2689x over previous
//
#include <hip/hip_runtime.h>
#include <math.h>

#define B_ 16
#define N_ 512
#define D_ 32
#define E_ 8176
#define SLEFT_ 16384
#define FSS_ 601
#define BN_ (B_*N_)            // 8192
#define BE_ (B_*E_)            // 130816
#define NSROW_ (SLEFT_ + 2*E_) // 32736
#define OUT_R_ (B_*FSS_)       // 9616

typedef __attribute__((ext_vector_type(8))) short short8;
typedef __attribute__((ext_vector_type(4))) float f32x4;

__device__ __forceinline__ ushort f2b(float f) {
  uint u = __builtin_bit_cast(uint, f);
  u += 0x7FFFu + ((u >> 16) & 1u);
  return (ushort)(u >> 16);
}
__device__ __forceinline__ float b2f(ushort h) {
  return __builtin_bit_cast(float, ((uint)h) << 16);
}

// ---------------- index / CSR build (once, reused by all 8 layers) --------

__global__ __launch_bounds__(256) void k_indices(const float* __restrict__ ns,
                                                 int* __restrict__ src_i,
                                                 int* __restrict__ dst_i,
                                                 int* __restrict__ cnt) {
  int idx = blockIdx.x*256 + threadIdx.x;
  if (idx >= BE_) return;
  int b = idx / E_;
  int j = idx - b*E_;
  const float* row = ns + (size_t)b*NSROW_;
  int s = (int)row[SLEFT_ + j];
  int r = (int)row[SLEFT_ + E_ + j];
  src_i[idx] = b*N_ + s;
  int dst = b*N_ + r;
  dst_i[idx] = dst;
  atomicAdd(&cnt[dst], 1);
}

__global__ __launch_bounds__(1024) void k_scan(const int* __restrict__ cnt,
                                               int* __restrict__ rowptr) {
  __shared__ int part[1024];
  int t = threadIdx.x;
  int base = t*8;
  int loc[8]; int s = 0;
  #pragma unroll
  for (int i=0;i<8;i++){ loc[i]=cnt[base+i]; s+=loc[i]; }
  part[t]=s; __syncthreads();
  for (int off=1; off<1024; off<<=1) {
    int v = (t>=off)?part[t-off]:0;
    __syncthreads();
    part[t]+=v;
    __syncthreads();
  }
  int ex = (t==0)?0:part[t-1];
  #pragma unroll
  for (int i=0;i<8;i++){ rowptr[base+i]=ex; ex+=loc[i]; }
  if (t==1023) rowptr[BN_]=ex;
}

__global__ __launch_bounds__(256) void k_scatter(const int* __restrict__ src_i,
                                                 const int* __restrict__ dst_i,
                                                 const int* __restrict__ rowptr,
                                                 int* __restrict__ fill,
                                                 int* __restrict__ csr_src) {
  int idx = blockIdx.x*256+threadIdx.x;
  if (idx>=BE_) return;
  int dst = dst_i[idx];
  int pos = rowptr[dst] + atomicAdd(&fill[dst],1);
  csr_src[pos] = src_i[idx];
}

// ---------------- sa (bf16, padded to K=64) ----------------

__global__ __launch_bounds__(256) void k_sa(const float* __restrict__ ns,
                                            const int* __restrict__ a,
                                            ushort* __restrict__ sa) {
  int idx = blockIdx.x*256+threadIdx.x;  // over BN_*64
  if (idx >= BN_*64) return;
  int v = idx >> 6, c = idx & 63;
  int b = v >> 9, n = v & 511;
  float val = 0.f;
  if (c < 32)       val = ns[(size_t)b*NSROW_ + n*32 + c];
  else if (c == 32) val = (a[b]==n) ? 1.f : 0.f;
  sa[idx] = f2b(val);
}

// ---------------- weight transpose + bf16 cast ----------------
// W [din][dout] fp32 -> Wt [Npadt][Kpad] bf16, zero padded.

__global__ __launch_bounds__(256) void k_wt(const float* __restrict__ W,
                                            ushort* __restrict__ Wt,
                                            int din, int dout, int Kpad, int Npadt) {
  int idx = blockIdx.x*256+threadIdx.x;
  if (idx >= Kpad*Npadt) return;
  int k = idx / Npadt, n = idx - k*Npadt;   // reads coalesced over n
  float v = (k < din && n < dout) ? W[(size_t)k*dout + n] : 0.f;
  Wt[(size_t)n*Kpad + k] = f2b(v);
}

// ---------------- MFMA bf16 GEMM: C[M][ldc](bf16) = A[M][Kpad] * Wt^T ----
// 128x128 tile, 4 waves each 64x64 via 4x4 grid of 16x16x32 MFMAs.

__global__ __launch_bounds__(256) void k_mfma_gemm(const ushort* __restrict__ A,
                                                   const ushort* __restrict__ Bt,
                                                   ushort* __restrict__ C,
                                                   int Kpad, int ldc, int Nout) {
  __shared__ ushort Asm[128*40];
  __shared__ ushort Bsm[128*40];
  int tid = threadIdx.x;
  int rowBase = blockIdx.y * 128;
  int colBase = blockIdx.x * 128;
  int wave = tid >> 6, lane = tid & 63;
  int wr = (wave >> 1) * 64, wc = (wave & 1) * 64;
  int lm = lane & 15, lk = (lane >> 4) * 8;

  f32x4 acc[4][4];
  #pragma unroll
  for (int i=0;i<4;i++)
    #pragma unroll
    for (int j=0;j<4;j++) acc[i][j] = (f32x4){0.f,0.f,0.f,0.f};

  for (int k0 = 0; k0 < Kpad; k0 += 32) {
    #pragma unroll
    for (int i = 0; i < 2; i++) {
      int t2 = tid + i*256;
      int r = t2 >> 2, c8 = (t2 & 3) * 8;
      *(short8*)&Asm[r*40 + c8] = *(const short8*)&A[(size_t)(rowBase+r)*Kpad + k0 + c8];
      *(short8*)&Bsm[r*40 + c8] = *(const short8*)&Bt[(size_t)(colBase+r)*Kpad + k0 + c8];
    }
    __syncthreads();
    short8 af[4], bfr[4];
    #pragma unroll
    for (int i=0;i<4;i++) af[i]  = *(short8*)&Asm[(wr + i*16 + lm)*40 + lk];
    #pragma unroll
    for (int j=0;j<4;j++) bfr[j] = *(short8*)&Bsm[(wc + j*16 + lm)*40 + lk];
    #pragma unroll
    for (int i=0;i<4;i++)
      #pragma unroll
      for (int j=0;j<4;j++)
        acc[i][j] = __builtin_amdgcn_mfma_f32_16x16x32_bf16(af[i], bfr[j], acc[i][j], 0,0,0);
    __syncthreads();
  }
  // C/D layout: col = lane&15, row = (lane>>4)*4 + reg   [measured m89]
  int cr = lane >> 4;
  #pragma unroll
  for (int i=0;i<4;i++) {
    #pragma unroll
    for (int j=0;j<4;j++) {
      int col = colBase + wc + j*16 + lm;
      if (col < Nout) {
        #pragma unroll
        for (int g=0; g<4; g++) {
          int row = rowBase + wr + i*16 + cr*4 + g;
          C[(size_t)row*ldc + col] = f2b(acc[i][j][g]);
        }
      }
    }
  }
}

// ---------------- per-node attention scalars (from bf16 h) ----------------

__global__ __launch_bounds__(256) void k_esed(const ushort* __restrict__ h,
                                              const float* __restrict__ asrc,
                                              const float* __restrict__ adst,
                                              float* __restrict__ es,
                                              float* __restrict__ ed,
                                              int dout, int hld) {
  int wid = threadIdx.x>>6, lane = threadIdx.x&63;
  int v = blockIdx.x*4 + wid;
  const ushort* hv = h + (size_t)v*hld;
  float s=0.f, d=0.f;
  for (int c=lane;c<dout;c+=64){ float x=b2f(hv[c]); s+=x*asrc[c]; d+=x*adst[c]; }
  #pragma unroll
  for (int o=32;o;o>>=1){ s+=__shfl_xor(s,o,64); d+=__shfl_xor(d,o,64); }
  if (lane==0){ es[v]=s; ed[v]=d; }
}

// ---------------- softmax + aggregation (one wave per node, ushort8) ------

__global__ __launch_bounds__(256) void k_aggregate(const ushort* __restrict__ h,
                                                   const float* __restrict__ es,
                                                   const float* __restrict__ ed,
                                                   const int* __restrict__ rowptr,
                                                   const int* __restrict__ csr_src,
                                                   const float* __restrict__ bias,
                                                   ushort* __restrict__ g,
                                                   int dout, int hld) {
  int wid = threadIdx.x>>6, lane = threadIdx.x&63;
  int v = blockIdx.x*4 + wid;
  int s0 = rowptr[v], e0 = rowptr[v+1];
  float edv = ed[v];
  float m = -__builtin_inff();
  for (int j = s0 + lane; j < e0; j += 64) {
    float e = es[csr_src[j]] + edv;
    e = e > 0.f ? e : 0.2f*e;
    m = fmaxf(m, e);
  }
  #pragma unroll
  for (int o=32;o;o>>=1) m = fmaxf(m, __shfl_xor(m,o,64));
  float den = 0.f;
  for (int j = s0 + lane; j < e0; j += 64) {
    float e = es[csr_src[j]] + edv;
    e = e > 0.f ? e : 0.2f*e;
    den += __expf(e - m);
  }
  #pragma unroll
  for (int o=32;o;o>>=1) den += __shfl_xor(den,o,64);
  float scale = 1.f/(den + 1e-16f);

  int nch = hld >> 3;   // ushort8 chunks per row (<=80)
  float acc[2][8];
  #pragma unroll
  for (int k=0;k<2;k++)
    #pragma unroll
    for (int q=0;q<8;q++) acc[k][q]=0.f;

  for (int j = s0; j < e0; ++j) {
    int u = csr_src[j];
    float e = es[u] + edv;
    e = e > 0.f ? e : 0.2f*e;
    float w = __expf(e - m) * scale;
    const ushort* hu = h + (size_t)u*hld;
    #pragma unroll
    for (int k=0;k<2;k++) {
      int ch = lane + (k<<6);
      if (ch < nch) {
        short8 hv = *(const short8*)&hu[ch*8];
        #pragma unroll
        for (int q=0;q<8;q++) acc[k][q] += w * b2f((ushort)hv[q]);
      }
    }
  }
  ushort* gv = g + (size_t)v*hld;
  #pragma unroll
  for (int k=0;k<2;k++) {
    int ch = lane + (k<<6);
    if (ch < nch) {
      short8 ov;
      #pragma unroll
      for (int q=0;q<8;q++) {
        int c = ch*8+q;
        float val = (c < dout) ? acc[k][q] + bias[c] : 0.f;
        ov[q] = (short)f2b(val);
      }
      *(short8*)&gv[ch*8] = ov;
    }
  }
}

// ---------------- fused LayerNorm(node axis)+ReLU -> bf16 padded input ----
// grid: (ceil(Kpad/64), B), block 256 = 4 row-threads x 64 cols

__global__ __launch_bounds__(256) void k_ln_fused(const ushort* __restrict__ g,
                                                  const float* __restrict__ sc,
                                                  const float* __restrict__ of,
                                                  ushort* __restrict__ xb,
                                                  int ldg, int dout, int Kpad) {
  int b = blockIdx.y;
  int lc = threadIdx.x & 63, r0 = threadIdx.x >> 6;
  int c = blockIdx.x*64 + lc;
  bool act = c < dout;
  float s=0.f, q=0.f;
  if (act) {
    for (int n=r0; n<N_; n+=4) {
      float x = b2f(g[(size_t)(b*N_+n)*ldg + c]);
      s+=x; q+=x*x;
    }
  }
  __shared__ float S[4][64], Q[4][64];
  S[r0][lc]=s; Q[r0][lc]=q; __syncthreads();
  float st = S[0][lc]+S[1][lc]+S[2][lc]+S[3][lc];
  float qt = Q[0][lc]+Q[1][lc]+Q[2][lc]+Q[3][lc];
  float mu = st*(1.f/N_);
  float var = qt*(1.f/N_) - mu*mu;
  float rs = rsqrtf(var+1e-5f);
  float scl = act ? sc[c] : 0.f;
  float ofs = act ? of[c] : 0.f;
  if (c < Kpad) {
    for (int n=r0; n<N_; n+=4) {
      size_t gi = (size_t)(b*N_+n);
      float y = 0.f;
      if (act) {
        float x = b2f(g[gi*ldg + c]);
        y = (x-mu)*rs*scl + ofs;
        y = y>0.f ? y : 0.f;
      }
      xb[gi*Kpad + c] = f2b(y);
    }
  }
}

// ---------------- reward: sum over nodes ----------------

__global__ __launch_bounds__(256) void k_rsum(const ushort* __restrict__ g,
                                              float* __restrict__ out) {
  int b = blockIdx.y;
  int lc = threadIdx.x & 63, r0 = threadIdx.x>>6;
  int c = blockIdx.x*64 + lc;
  float s = 0.f;
  if (c < FSS_) for (int n=r0; n<N_; n+=4) s += b2f(g[(size_t)(b*N_+n)*640 + c]);
  __shared__ float S[4][64];
  S[r0][lc]=s; __syncthreads();
  if (r0==0 && c<FSS_) out[b*FSS_+c] = S[0][lc]+S[1][lc]+S[2][lc]+S[3][lc];
}

// ---------------- ns_new assembly ----------------

__global__ __launch_bounds__(256) void k_output(const ushort* __restrict__ f,
                                                const float* __restrict__ ns,
                                                float* __restrict__ out) {
  int idx = blockIdx.x*256+threadIdx.x;
  if (idx >= B_*NSROW_) return;
  int b = idx / NSROW_; int j = idx - b*NSROW_;
  float v = (j < SLEFT_) ? b2f(f[(size_t)b*SLEFT_ + j]) : ns[(size_t)b*NSROW_ + j];
  out[OUT_R_ + idx] = v;
}

// ---------------- host driver ----------------

static void gat_layer(const ushort* xb, int Kpad, int dout, int hld, int Npadt,
                      const ushort* Wt, const float* as, const float* ad, const float* bias,
                      const float* sc, const float* of, ushort* xb_next, int Kpad_next,
                      ushort* h, ushort* g, float* es, float* ed,
                      const int* rowptr, const int* csr_src, hipStream_t stream) {
  k_mfma_gemm<<<dim3(Npadt/128, BN_/128), 256, 0, stream>>>(xb, Wt, h, Kpad, hld, hld);
  k_esed<<<BN_/4, 256, 0, stream>>>(h, as, ad, es, ed, dout, hld);
  k_aggregate<<<BN_/4, 256, 0, stream>>>(h, es, ed, rowptr, csr_src, bias, g, dout, hld);
  if (sc)
    k_ln_fused<<<dim3((Kpad_next+63)/64, B_), 256, 0, stream>>>(g, sc, of, xb_next, hld, dout, Kpad_next);
}

extern "C" void kernel_launch(void* const* d_in, const int* in_sizes, int n_in,
                              void* d_out, int out_size, void* d_ws, size_t ws_size,
                              hipStream_t stream) {
  const float* ns = (const float*)d_in[0];
  const int*   a  = (const int*)d_in[1];

  const float *W[4], *As[4], *Ad[4], *Bb[4], *Sc[3], *Of[3];
  const float *rW[4], *rAs[4], *rAd[4], *rBb[4], *rSc[3], *rOf[3];
  int p = 2;
  for (int i=0;i<4;i++){
    W[i]=(const float*)d_in[p++]; As[i]=(const float*)d_in[p++];
    Ad[i]=(const float*)d_in[p++]; Bb[i]=(const float*)d_in[p++];
    if (i<3){ Sc[i]=(const float*)d_in[p++]; Of[i]=(const float*)d_in[p++]; }
  }
  for (int i=0;i<4;i++){
    rW[i]=(const float*)d_in[p++]; rAs[i]=(const float*)d_in[p++];
    rAd[i]=(const float*)d_in[p++]; rBb[i]=(const float*)d_in[p++];
    if (i<3){ rSc[i]=(const float*)d_in[p++]; rOf[i]=(const float*)d_in[p++]; }
  }

  char* w = (char*)d_ws;
  auto carve = [&](size_t bytes)->void* {
    void* r = (void*)w;
    w += (bytes + 255) & ~(size_t)255;
    return r;
  };
  ushort* xb   = (ushort*)carve((size_t)BN_*608*2);
  ushort* hbuf = (ushort*)carve((size_t)BN_*640*2);
  ushort* gbuf = (ushort*)carve((size_t)BN_*640*2);
  ushort* sabf = (ushort*)carve((size_t)BN_*64*2);
  float* es    = (float*)carve((size_t)BN_*4);
  float* ed    = (float*)carve((size_t)BN_*4);
  int* src_i   = (int*)carve((size_t)BE_*4);
  int* dst_i   = (int*)carve((size_t)BE_*4);
  int* cnt     = (int*)carve((size_t)BN_*4);
  int* rowptr  = (int*)carve((size_t)(BN_+1)*4);
  int* fill    = (int*)carve((size_t)BN_*4);
  int* csr_src = (int*)carve((size_t)BE_*4);
  // transposed bf16 weights: reward {640x64, 3x 640x608}, next {128x64,128x128,128x64,128x64}
  ushort* rWt[4]; ushort* nWt[4];
  rWt[0] = (ushort*)carve((size_t)640*64*2);
  for (int i=1;i<4;i++) rWt[i] = (ushort*)carve((size_t)640*608*2);
  nWt[0] = (ushort*)carve((size_t)128*64*2);
  nWt[1] = (ushort*)carve((size_t)128*128*2);
  nWt[2] = (ushort*)carve((size_t)128*64*2);
  nWt[3] = (ushort*)carve((size_t)128*64*2);

  float* out = (float*)d_out;

  hipMemsetAsync(cnt,  0, (size_t)BN_*4, stream);
  hipMemsetAsync(fill, 0, (size_t)BN_*4, stream);

  k_indices<<<(BE_+255)/256, 256, 0, stream>>>(ns, src_i, dst_i, cnt);
  k_scan<<<1, 1024, 0, stream>>>(cnt, rowptr);
  k_scatter<<<(BE_+255)/256, 256, 0, stream>>>(src_i, dst_i, rowptr, fill, csr_src);
  k_sa<<<(BN_*64+255)/256, 256, 0, stream>>>(ns, a, sabf);

  // weight transposes (layer dims: reward 33->601,601->601 x3; next 33->128,128->64,64->64,64->32)
  k_wt<<<(64*640+255)/256, 256, 0, stream>>>(rW[0], rWt[0], 33, 601, 64, 640);
  for (int i=1;i<4;i++)
    k_wt<<<(608*640+255)/256, 256, 0, stream>>>(rW[i], rWt[i], 601, 601, 608, 640);
  k_wt<<<(64*128+255)/256, 256, 0, stream>>>(W[0], nWt[0], 33, 128, 64, 128);
  k_wt<<<(128*128+255)/256, 256, 0, stream>>>(W[1], nWt[1], 128, 64, 128, 128);
  k_wt<<<(64*128+255)/256, 256, 0, stream>>>(W[2], nWt[2], 64, 64, 64, 128);
  k_wt<<<(64*128+255)/256, 256, 0, stream>>>(W[3], nWt[3], 64, 32, 64, 128);

  // reward head:   (Kpad,dout,hld,Npadt, Kpad_next)
  gat_layer(sabf, 64,  FSS_, 640, 640, rWt[0], rAs[0],rAd[0],rBb[0], rSc[0],rOf[0], xb, 608, hbuf, gbuf, es, ed, rowptr, csr_src, stream);
  gat_layer(xb,   608, FSS_, 640, 640, rWt[1], rAs[1],rAd[1],rBb[1], rSc[1],rOf[1], xb, 608, hbuf, gbuf, es, ed, rowptr, csr_src, stream);
  gat_layer(xb,   608, FSS_, 640, 640, rWt[2], rAs[2],rAd[2],rBb[2], rSc[2],rOf[2], xb, 608, hbuf, gbuf, es, ed, rowptr, csr_src, stream);
  gat_layer(xb,   608, FSS_, 640, 640, rWt[3], rAs[3],rAd[3],rBb[3], nullptr,nullptr, nullptr, 0, hbuf, gbuf, es, ed, rowptr, csr_src, stream);
  k_rsum<<<dim3(10, B_), 256, 0, stream>>>(gbuf, out);

  // next-state head
  gat_layer(sabf, 64,  128, 128, 128, nWt[0], As[0],Ad[0],Bb[0], Sc[0],Of[0], xb, 128, hbuf, gbuf, es, ed, rowptr, csr_src, stream);
  gat_layer(xb,   128, 64,  64,  128, nWt[1], As[1],Ad[1],Bb[1], Sc[1],Of[1], xb, 64,  hbuf, gbuf, es, ed, rowptr, csr_src, stream);
  gat_layer(xb,   64,  64,  64,  128, nWt[2], As[2],Ad[2],Bb[2], Sc[2],Of[2], xb, 64,  hbuf, gbuf, es, ed, rowptr, csr_src, stream);
  gat_layer(xb,   64,  32,  32,  128, nWt[3], As[3],Ad[3],Bb[3], nullptr,nullptr, nullptr, 0, hbuf, gbuf, es, ed, rowptr, csr_src, stream);
  k_output<<<(B_*NSROW_+255)/256, 256, 0, stream>>>(gbuf, ns, out);
}

// Round 3
// 667.250 us; speedup vs baseline: 1.8428x; 1.4523x over previous
//
#include <hip/hip_runtime.h>
#include <math.h>

#define B_ 16
#define N_ 512
#define D_ 32
#define E_ 8176
#define SLEFT_ 16384
#define FSS_ 601
#define BN_ (B_*N_)            // 8192
#define BE_ (B_*E_)            // 130816
#define NSROW_ (SLEFT_ + 2*E_) // 32736
#define OUT_R_ (B_*FSS_)       // 9616

typedef __attribute__((ext_vector_type(8))) short short8;
typedef __attribute__((ext_vector_type(4))) float f32x4;

__device__ __forceinline__ ushort f2b(float f) {
  uint u = __builtin_bit_cast(uint, f);
  u += 0x7FFFu + ((u >> 16) & 1u);
  return (ushort)(u >> 16);
}
__device__ __forceinline__ float b2f(ushort h) {
  return __builtin_bit_cast(float, ((uint)h) << 16);
}

// ---------------- index / CSR build (once, reused by all 8 layers) --------

__global__ __launch_bounds__(256) void k_indices(const float* __restrict__ ns,
                                                 int* __restrict__ src_i,
                                                 int* __restrict__ dst_i,
                                                 int* __restrict__ cnt) {
  int idx = blockIdx.x*256 + threadIdx.x;
  if (idx >= BE_) return;
  int b = idx / E_;
  int j = idx - b*E_;
  const float* row = ns + (size_t)b*NSROW_;
  int s = (int)row[SLEFT_ + j];
  int r = (int)row[SLEFT_ + E_ + j];
  src_i[idx] = b*N_ + s;
  int dst = b*N_ + r;
  dst_i[idx] = dst;
  atomicAdd(&cnt[dst], 1);
}

__global__ __launch_bounds__(1024) void k_scan(const int* __restrict__ cnt,
                                               int* __restrict__ rowptr) {
  __shared__ int part[1024];
  int t = threadIdx.x;
  int base = t*8;
  int loc[8]; int s = 0;
  #pragma unroll
  for (int i=0;i<8;i++){ loc[i]=cnt[base+i]; s+=loc[i]; }
  part[t]=s; __syncthreads();
  for (int off=1; off<1024; off<<=1) {
    int v = (t>=off)?part[t-off]:0;
    __syncthreads();
    part[t]+=v;
    __syncthreads();
  }
  int ex = (t==0)?0:part[t-1];
  #pragma unroll
  for (int i=0;i<8;i++){ rowptr[base+i]=ex; ex+=loc[i]; }
  if (t==1023) rowptr[BN_]=ex;
}

__global__ __launch_bounds__(256) void k_scatter(const int* __restrict__ src_i,
                                                 const int* __restrict__ dst_i,
                                                 const int* __restrict__ rowptr,
                                                 int* __restrict__ fill,
                                                 int* __restrict__ csr_src) {
  int idx = blockIdx.x*256+threadIdx.x;
  if (idx>=BE_) return;
  int dst = dst_i[idx];
  int pos = rowptr[dst] + atomicAdd(&fill[dst],1);
  csr_src[pos] = src_i[idx];
}

// ---------------- sa (bf16, padded to K=64) ----------------

__global__ __launch_bounds__(256) void k_sa(const float* __restrict__ ns,
                                            const int* __restrict__ a,
                                            ushort* __restrict__ sa) {
  int idx = blockIdx.x*256+threadIdx.x;  // over BN_*64
  if (idx >= BN_*64) return;
  int v = idx >> 6, c = idx & 63;
  int b = v >> 9, n = v & 511;
  float val = 0.f;
  if (c < 32)       val = ns[(size_t)b*NSROW_ + n*32 + c];
  else if (c == 32) val = (a[b]==n) ? 1.f : 0.f;
  sa[idx] = f2b(val);
}

// ---------------- weight transpose + bf16 cast ----------------

__global__ __launch_bounds__(256) void k_wt(const float* __restrict__ W,
                                            ushort* __restrict__ Wt,
                                            int din, int dout, int Kpad, int Npadt) {
  int idx = blockIdx.x*256+threadIdx.x;
  if (idx >= Kpad*Npadt) return;
  int k = idx / Npadt, n = idx - k*Npadt;
  float v = (k < din && n < dout) ? W[(size_t)k*dout + n] : 0.f;
  Wt[(size_t)n*Kpad + k] = f2b(v);
}

// ---------------- MFMA bf16 GEMM ----------------

__global__ __launch_bounds__(256) void k_mfma_gemm(const ushort* __restrict__ A,
                                                   const ushort* __restrict__ Bt,
                                                   ushort* __restrict__ C,
                                                   int Kpad, int ldc, int Nout) {
  __shared__ ushort Asm[128*40];
  __shared__ ushort Bsm[128*40];
  int tid = threadIdx.x;
  int rowBase = blockIdx.y * 128;
  int colBase = blockIdx.x * 128;
  int wave = tid >> 6, lane = tid & 63;
  int wr = (wave >> 1) * 64, wc = (wave & 1) * 64;
  int lm = lane & 15, lk = (lane >> 4) * 8;

  f32x4 acc[4][4];
  #pragma unroll
  for (int i=0;i<4;i++)
    #pragma unroll
    for (int j=0;j<4;j++) acc[i][j] = (f32x4){0.f,0.f,0.f,0.f};

  for (int k0 = 0; k0 < Kpad; k0 += 32) {
    #pragma unroll
    for (int i = 0; i < 2; i++) {
      int t2 = tid + i*256;
      int r = t2 >> 2, c8 = (t2 & 3) * 8;
      *(short8*)&Asm[r*40 + c8] = *(const short8*)&A[(size_t)(rowBase+r)*Kpad + k0 + c8];
      *(short8*)&Bsm[r*40 + c8] = *(const short8*)&Bt[(size_t)(colBase+r)*Kpad + k0 + c8];
    }
    __syncthreads();
    short8 af[4], bfr[4];
    #pragma unroll
    for (int i=0;i<4;i++) af[i]  = *(short8*)&Asm[(wr + i*16 + lm)*40 + lk];
    #pragma unroll
    for (int j=0;j<4;j++) bfr[j] = *(short8*)&Bsm[(wc + j*16 + lm)*40 + lk];
    #pragma unroll
    for (int i=0;i<4;i++)
      #pragma unroll
      for (int j=0;j<4;j++)
        acc[i][j] = __builtin_amdgcn_mfma_f32_16x16x32_bf16(af[i], bfr[j], acc[i][j], 0,0,0);
    __syncthreads();
  }
  int cr = lane >> 4;
  #pragma unroll
  for (int i=0;i<4;i++) {
    #pragma unroll
    for (int j=0;j<4;j++) {
      int col = colBase + wc + j*16 + lm;
      if (col < Nout) {
        #pragma unroll
        for (int g=0; g<4; g++) {
          int row = rowBase + wr + i*16 + cr*4 + g;
          C[(size_t)row*ldc + col] = f2b(acc[i][j][g]);
        }
      }
    }
  }
}

// ---------------- per-node attention scalars ----------------

__global__ __launch_bounds__(256) void k_esed(const ushort* __restrict__ h,
                                              const float* __restrict__ asrc,
                                              const float* __restrict__ adst,
                                              float* __restrict__ es,
                                              float* __restrict__ ed,
                                              int dout, int hld) {
  int wid = threadIdx.x>>6, lane = threadIdx.x&63;
  int v = blockIdx.x*4 + wid;
  const ushort* hv = h + (size_t)v*hld;
  float s=0.f, d=0.f;
  for (int c=lane;c<dout;c+=64){ float x=b2f(hv[c]); s+=x*asrc[c]; d+=x*adst[c]; }
  #pragma unroll
  for (int o=32;o;o>>=1){ s+=__shfl_xor(s,o,64); d+=__shfl_xor(d,o,64); }
  if (lane==0){ es[v]=s; ed[v]=d; }
}

// ---------------- softmax + aggregation (one wave per node) ------

__global__ __launch_bounds__(256) void k_aggregate(const ushort* __restrict__ h,
                                                   const float* __restrict__ es,
                                                   const float* __restrict__ ed,
                                                   const int* __restrict__ rowptr,
                                                   const int* __restrict__ csr_src,
                                                   const float* __restrict__ bias,
                                                   ushort* __restrict__ g,
                                                   int dout, int hld) {
  int wid = threadIdx.x>>6, lane = threadIdx.x&63;
  int v = blockIdx.x*4 + wid;
  int s0 = rowptr[v], e0 = rowptr[v+1];
  float edv = ed[v];
  float m = -__builtin_inff();
  for (int j = s0 + lane; j < e0; j += 64) {
    float e = es[csr_src[j]] + edv;
    e = e > 0.f ? e : 0.2f*e;
    m = fmaxf(m, e);
  }
  #pragma unroll
  for (int o=32;o;o>>=1) m = fmaxf(m, __shfl_xor(m,o,64));
  float den = 0.f;
  for (int j = s0 + lane; j < e0; j += 64) {
    float e = es[csr_src[j]] + edv;
    e = e > 0.f ? e : 0.2f*e;
    den += __expf(e - m);
  }
  #pragma unroll
  for (int o=32;o;o>>=1) den += __shfl_xor(den,o,64);
  float scale = 1.f/(den + 1e-16f);

  int nch = hld >> 3;
  float acc[2][8];
  #pragma unroll
  for (int k=0;k<2;k++)
    #pragma unroll
    for (int q=0;q<8;q++) acc[k][q]=0.f;

  for (int j = s0; j < e0; ++j) {
    int u = csr_src[j];
    float e = es[u] + edv;
    e = e > 0.f ? e : 0.2f*e;
    float w = __expf(e - m) * scale;
    const ushort* hu = h + (size_t)u*hld;
    #pragma unroll
    for (int k=0;k<2;k++) {
      int ch = lane + (k<<6);
      if (ch < nch) {
        short8 hv = *(const short8*)&hu[ch*8];
        #pragma unroll
        for (int q=0;q<8;q++) acc[k][q] += w * b2f((ushort)hv[q]);
      }
    }
  }
  ushort* gv = g + (size_t)v*hld;
  #pragma unroll
  for (int k=0;k<2;k++) {
    int ch = lane + (k<<6);
    if (ch < nch) {
      short8 ov;
      #pragma unroll
      for (int q=0;q<8;q++) {
        int c = ch*8+q;
        float val = (c < dout) ? acc[k][q] + bias[c] : 0.f;
        ov[q] = (short)f2b(val);
      }
      *(short8*)&gv[ch*8] = ov;
    }
  }
}

// ---------------- LN stats: grid (cols/64, B, 8 node-chunks) ----------------

__global__ __launch_bounds__(256) void k_ln_stats2(const ushort* __restrict__ g,
                                                   float* __restrict__ stats,
                                                   int ldg, int dout) {
  int b = blockIdx.y; int n0 = blockIdx.z*64;
  int lc = threadIdx.x & 63, r0 = threadIdx.x >> 6;
  int c = blockIdx.x*64 + lc;
  float s=0.f, q=0.f;
  if (c < dout) {
    #pragma unroll 4
    for (int i=0;i<16;i++) {
      int n = n0 + r0*16 + i;
      float x = b2f(g[(size_t)(b*N_+n)*ldg + c]);
      s+=x; q+=x*x;
    }
  }
  __shared__ float S[4][64], Q[4][64];
  S[r0][lc]=s; Q[r0][lc]=q; __syncthreads();
  if (r0==0 && c<dout) {
    atomicAdd(&stats[(size_t)b*dout+c],      S[0][lc]+S[1][lc]+S[2][lc]+S[3][lc]);
    atomicAdd(&stats[(size_t)(B_+b)*dout+c], Q[0][lc]+Q[1][lc]+Q[2][lc]+Q[3][lc]);
  }
}

// ---------------- LN apply + ReLU -> padded bf16 input (elementwise) ------
// block 256 = 2 rows x 128 col-pairs; grid (ceil(Kpad/256), BN/2)

__global__ __launch_bounds__(256) void k_ln_apply2(const ushort* __restrict__ g,
                                                   const float* __restrict__ stats,
                                                   const float* __restrict__ sc,
                                                   const float* __restrict__ of,
                                                   ushort* __restrict__ xb,
                                                   int ldg, int dout, int Kpad) {
  int tid = threadIdx.x;
  int p = blockIdx.x*128 + (tid & 127);       // column-pair index
  int v = blockIdx.y*2 + (tid >> 7);
  int c0 = p*2;
  if (c0 >= Kpad) return;
  int b = v >> 9;
  uint gg = *(const uint*)&g[(size_t)v*ldg + c0];
  ushort r01[2] = {(ushort)(gg & 0xFFFFu), (ushort)(gg >> 16)};
  ushort ov[2];
  #pragma unroll
  for (int q=0;q<2;q++) {
    int c = c0+q;
    float y = 0.f;
    if (c < dout) {
      float mu  = stats[(size_t)b*dout+c] * (1.f/N_);
      float var = stats[(size_t)(B_+b)*dout+c]*(1.f/N_) - mu*mu;
      float x = b2f(r01[q]);
      y = (x-mu)*rsqrtf(var+1e-5f)*sc[c] + of[c];
      y = y>0.f ? y : 0.f;
    }
    ov[q] = f2b(y);
  }
  *(uint*)&xb[(size_t)v*Kpad + c0] = ((uint)ov[1]<<16) | ov[0];
}

// ---------------- reward: sum over nodes (8-way split + atomic) -----------

__global__ __launch_bounds__(256) void k_rsum(const ushort* __restrict__ g,
                                              float* __restrict__ out) {
  int b = blockIdx.y; int n0 = blockIdx.z*64;
  int lc = threadIdx.x & 63, r0 = threadIdx.x>>6;
  int c = blockIdx.x*64 + lc;
  float s = 0.f;
  if (c < FSS_) {
    #pragma unroll 4
    for (int i=0;i<16;i++) {
      int n = n0 + r0*16 + i;
      s += b2f(g[(size_t)(b*N_+n)*640 + c]);
    }
  }
  __shared__ float S[4][64];
  S[r0][lc]=s; __syncthreads();
  if (r0==0 && c<FSS_)
    atomicAdd(&out[b*FSS_+c], S[0][lc]+S[1][lc]+S[2][lc]+S[3][lc]);
}

// ---------------- ns_new assembly ----------------

__global__ __launch_bounds__(256) void k_output(const ushort* __restrict__ f,
                                                const float* __restrict__ ns,
                                                float* __restrict__ out) {
  int idx = blockIdx.x*256+threadIdx.x;
  if (idx >= B_*NSROW_) return;
  int b = idx / NSROW_; int j = idx - b*NSROW_;
  float v = (j < SLEFT_) ? b2f(f[(size_t)b*SLEFT_ + j]) : ns[(size_t)b*NSROW_ + j];
  out[OUT_R_ + idx] = v;
}

// ---------------- host driver ----------------

static void gat_layer(const ushort* xb, int Kpad, int dout, int hld, int Npadt,
                      const ushort* Wt, const float* as, const float* ad, const float* bias,
                      const float* sc, const float* of, ushort* xb_next, int Kpad_next,
                      ushort* h, ushort* g, float* es, float* ed, float* stats,
                      const int* rowptr, const int* csr_src, hipStream_t stream) {
  k_mfma_gemm<<<dim3(Npadt/128, BN_/128), 256, 0, stream>>>(xb, Wt, h, Kpad, hld, hld);
  k_esed<<<BN_/4, 256, 0, stream>>>(h, as, ad, es, ed, dout, hld);
  k_aggregate<<<BN_/4, 256, 0, stream>>>(h, es, ed, rowptr, csr_src, bias, g, dout, hld);
  if (sc) {
    hipMemsetAsync(stats, 0, (size_t)2*B_*dout*sizeof(float), stream);
    k_ln_stats2<<<dim3((dout+63)/64, B_, 8), 256, 0, stream>>>(g, stats, hld, dout);
    k_ln_apply2<<<dim3((Kpad_next+255)/256, BN_/2), 256, 0, stream>>>(g, stats, sc, of, xb_next, hld, dout, Kpad_next);
  }
}

extern "C" void kernel_launch(void* const* d_in, const int* in_sizes, int n_in,
                              void* d_out, int out_size, void* d_ws, size_t ws_size,
                              hipStream_t stream) {
  const float* ns = (const float*)d_in[0];
  const int*   a  = (const int*)d_in[1];

  const float *W[4], *As[4], *Ad[4], *Bb[4], *Sc[3], *Of[3];
  const float *rW[4], *rAs[4], *rAd[4], *rBb[4], *rSc[3], *rOf[3];
  int p = 2;
  for (int i=0;i<4;i++){
    W[i]=(const float*)d_in[p++]; As[i]=(const float*)d_in[p++];
    Ad[i]=(const float*)d_in[p++]; Bb[i]=(const float*)d_in[p++];
    if (i<3){ Sc[i]=(const float*)d_in[p++]; Of[i]=(const float*)d_in[p++]; }
  }
  for (int i=0;i<4;i++){
    rW[i]=(const float*)d_in[p++]; rAs[i]=(const float*)d_in[p++];
    rAd[i]=(const float*)d_in[p++]; rBb[i]=(const float*)d_in[p++];
    if (i<3){ rSc[i]=(const float*)d_in[p++]; rOf[i]=(const float*)d_in[p++]; }
  }

  char* w = (char*)d_ws;
  auto carve = [&](size_t bytes)->void* {
    void* r = (void*)w;
    w += (bytes + 255) & ~(size_t)255;
    return r;
  };
  ushort* xb   = (ushort*)carve((size_t)BN_*608*2);
  ushort* hbuf = (ushort*)carve((size_t)BN_*640*2);
  ushort* gbuf = (ushort*)carve((size_t)BN_*640*2);
  ushort* sabf = (ushort*)carve((size_t)BN_*64*2);
  float* es    = (float*)carve((size_t)BN_*4);
  float* ed    = (float*)carve((size_t)BN_*4);
  float* stats = (float*)carve((size_t)2*B_*FSS_*4);
  int* src_i   = (int*)carve((size_t)BE_*4);
  int* dst_i   = (int*)carve((size_t)BE_*4);
  int* cnt     = (int*)carve((size_t)BN_*4);
  int* rowptr  = (int*)carve((size_t)(BN_+1)*4);
  int* fill    = (int*)carve((size_t)BN_*4);
  int* csr_src = (int*)carve((size_t)BE_*4);
  ushort* rWt[4]; ushort* nWt[4];
  rWt[0] = (ushort*)carve((size_t)640*64*2);
  for (int i=1;i<4;i++) rWt[i] = (ushort*)carve((size_t)640*608*2);
  nWt[0] = (ushort*)carve((size_t)128*64*2);
  nWt[1] = (ushort*)carve((size_t)128*128*2);
  nWt[2] = (ushort*)carve((size_t)128*64*2);
  nWt[3] = (ushort*)carve((size_t)128*64*2);

  float* out = (float*)d_out;

  hipMemsetAsync(cnt,  0, (size_t)BN_*4, stream);
  hipMemsetAsync(fill, 0, (size_t)BN_*4, stream);
  hipMemsetAsync(out,  0, (size_t)OUT_R_*4, stream);

  k_indices<<<(BE_+255)/256, 256, 0, stream>>>(ns, src_i, dst_i, cnt);
  k_scan<<<1, 1024, 0, stream>>>(cnt, rowptr);
  k_scatter<<<(BE_+255)/256, 256, 0, stream>>>(src_i, dst_i, rowptr, fill, csr_src);
  k_sa<<<(BN_*64+255)/256, 256, 0, stream>>>(ns, a, sabf);

  k_wt<<<(64*640+255)/256, 256, 0, stream>>>(rW[0], rWt[0], 33, 601, 64, 640);
  for (int i=1;i<4;i++)
    k_wt<<<(608*640+255)/256, 256, 0, stream>>>(rW[i], rWt[i], 601, 601, 608, 640);
  k_wt<<<(64*128+255)/256, 256, 0, stream>>>(W[0], nWt[0], 33, 128, 64, 128);
  k_wt<<<(128*128+255)/256, 256, 0, stream>>>(W[1], nWt[1], 128, 64, 128, 128);
  k_wt<<<(64*128+255)/256, 256, 0, stream>>>(W[2], nWt[2], 64, 64, 64, 128);
  k_wt<<<(64*128+255)/256, 256, 0, stream>>>(W[3], nWt[3], 64, 32, 64, 128);

  // reward head
  gat_layer(sabf, 64,  FSS_, 640, 640, rWt[0], rAs[0],rAd[0],rBb[0], rSc[0],rOf[0], xb, 608, hbuf, gbuf, es, ed, stats, rowptr, csr_src, stream);
  gat_layer(xb,   608, FSS_, 640, 640, rWt[1], rAs[1],rAd[1],rBb[1], rSc[1],rOf[1], xb, 608, hbuf, gbuf, es, ed, stats, rowptr, csr_src, stream);
  gat_layer(xb,   608, FSS_, 640, 640, rWt[2], rAs[2],rAd[2],rBb[2], rSc[2],rOf[2], xb, 608, hbuf, gbuf, es, ed, stats, rowptr, csr_src, stream);
  gat_layer(xb,   608, FSS_, 640, 640, rWt[3], rAs[3],rAd[3],rBb[3], nullptr,nullptr, nullptr, 0, hbuf, gbuf, es, ed, stats, rowptr, csr_src, stream);
  k_rsum<<<dim3(10, B_, 8), 256, 0, stream>>>(gbuf, out);

  // next-state head
  gat_layer(sabf, 64,  128, 128, 128, nWt[0], As[0],Ad[0],Bb[0], Sc[0],Of[0], xb, 128, hbuf, gbuf, es, ed, stats, rowptr, csr_src, stream);
  gat_layer(xb,   128, 64,  64,  128, nWt[1], As[1],Ad[1],Bb[1], Sc[1],Of[1], xb, 64,  hbuf, gbuf, es, ed, stats, rowptr, csr_src, stream);
  gat_layer(xb,   64,  64,  64,  128, nWt[2], As[2],Ad[2],Bb[2], Sc[2],Of[2], xb, 64,  hbuf, gbuf, es, ed, stats, rowptr, csr_src, stream);
  gat_layer(xb,   64,  32,  32,  128, nWt[3], As[3],Ad[3],Bb[3], nullptr,nullptr, nullptr, 0, hbuf, gbuf, es, ed, stats, rowptr, csr_src, stream);
  k_output<<<(B_*NSROW_+255)/256, 256, 0, stream>>>(gbuf, ns, out);
}

// Round 4
// 608.236 us; speedup vs baseline: 2.0216x; 1.0970x over previous
//
#include <hip/hip_runtime.h>
#include <math.h>

#define B_ 16
#define N_ 512
#define D_ 32
#define E_ 8176
#define SLEFT_ 16384
#define FSS_ 601
#define BN_ (B_*N_)            // 8192
#define BE_ (B_*E_)            // 130816
#define NSROW_ (SLEFT_ + 2*E_) // 32736
#define OUT_R_ (B_*FSS_)       // 9616

typedef __attribute__((ext_vector_type(8))) short short8;
typedef __attribute__((ext_vector_type(4))) float f32x4;

__device__ __forceinline__ ushort f2b(float f) {
  uint u = __builtin_bit_cast(uint, f);
  u += 0x7FFFu + ((u >> 16) & 1u);
  return (ushort)(u >> 16);
}
__device__ __forceinline__ float b2f(ushort h) {
  return __builtin_bit_cast(float, ((uint)h) << 16);
}

// ---------------- index / CSR build (once, reused by all 8 layers) --------

__global__ __launch_bounds__(256) void k_indices(const float* __restrict__ ns,
                                                 int* __restrict__ src_i,
                                                 int* __restrict__ dst_i,
                                                 int* __restrict__ cnt) {
  int idx = blockIdx.x*256 + threadIdx.x;
  if (idx >= BE_) return;
  int b = idx / E_;
  int j = idx - b*E_;
  const float* row = ns + (size_t)b*NSROW_;
  int s = (int)row[SLEFT_ + j];
  int r = (int)row[SLEFT_ + E_ + j];
  src_i[idx] = b*N_ + s;
  int dst = b*N_ + r;
  dst_i[idx] = dst;
  atomicAdd(&cnt[dst], 1);
}

__global__ __launch_bounds__(1024) void k_scan(const int* __restrict__ cnt,
                                               int* __restrict__ rowptr) {
  __shared__ int part[1024];
  int t = threadIdx.x;
  int base = t*8;
  int loc[8]; int s = 0;
  #pragma unroll
  for (int i=0;i<8;i++){ loc[i]=cnt[base+i]; s+=loc[i]; }
  part[t]=s; __syncthreads();
  for (int off=1; off<1024; off<<=1) {
    int v = (t>=off)?part[t-off]:0;
    __syncthreads();
    part[t]+=v;
    __syncthreads();
  }
  int ex = (t==0)?0:part[t-1];
  #pragma unroll
  for (int i=0;i<8;i++){ rowptr[base+i]=ex; ex+=loc[i]; }
  if (t==1023) rowptr[BN_]=ex;
}

__global__ __launch_bounds__(256) void k_scatter(const int* __restrict__ src_i,
                                                 const int* __restrict__ dst_i,
                                                 const int* __restrict__ rowptr,
                                                 int* __restrict__ fill,
                                                 int* __restrict__ csr_src) {
  int idx = blockIdx.x*256+threadIdx.x;
  if (idx>=BE_) return;
  int dst = dst_i[idx];
  int pos = rowptr[dst] + atomicAdd(&fill[dst],1);
  csr_src[pos] = src_i[idx];
}

// ---------------- sa (bf16, padded to K=64) ----------------

__global__ __launch_bounds__(256) void k_sa(const float* __restrict__ ns,
                                            const int* __restrict__ a,
                                            ushort* __restrict__ sa) {
  int idx = blockIdx.x*256+threadIdx.x;  // over BN_*64
  if (idx >= BN_*64) return;
  int v = idx >> 6, c = idx & 63;
  int b = v >> 9, n = v & 511;
  float val = 0.f;
  if (c < 32)       val = ns[(size_t)b*NSROW_ + n*32 + c];
  else if (c == 32) val = (a[b]==n) ? 1.f : 0.f;
  sa[idx] = f2b(val);
}

// ---------------- weight transpose + bf16 cast ----------------

__global__ __launch_bounds__(256) void k_wt(const float* __restrict__ W,
                                            ushort* __restrict__ Wt,
                                            int din, int dout, int Kpad, int Npadt) {
  int idx = blockIdx.x*256+threadIdx.x;
  if (idx >= Kpad*Npadt) return;
  int k = idx / Npadt, n = idx - k*Npadt;
  float v = (k < din && n < dout) ? W[(size_t)k*dout + n] : 0.f;
  Wt[(size_t)n*Kpad + k] = f2b(v);
}

// ---------------- MFMA bf16 GEMM ----------------

__global__ __launch_bounds__(256) void k_mfma_gemm(const ushort* __restrict__ A,
                                                   const ushort* __restrict__ Bt,
                                                   ushort* __restrict__ C,
                                                   int Kpad, int ldc, int Nout) {
  __shared__ ushort Asm[128*40];
  __shared__ ushort Bsm[128*40];
  int tid = threadIdx.x;
  int rowBase = blockIdx.y * 128;
  int colBase = blockIdx.x * 128;
  int wave = tid >> 6, lane = tid & 63;
  int wr = (wave >> 1) * 64, wc = (wave & 1) * 64;
  int lm = lane & 15, lk = (lane >> 4) * 8;

  f32x4 acc[4][4];
  #pragma unroll
  for (int i=0;i<4;i++)
    #pragma unroll
    for (int j=0;j<4;j++) acc[i][j] = (f32x4){0.f,0.f,0.f,0.f};

  for (int k0 = 0; k0 < Kpad; k0 += 32) {
    #pragma unroll
    for (int i = 0; i < 2; i++) {
      int t2 = tid + i*256;
      int r = t2 >> 2, c8 = (t2 & 3) * 8;
      *(short8*)&Asm[r*40 + c8] = *(const short8*)&A[(size_t)(rowBase+r)*Kpad + k0 + c8];
      *(short8*)&Bsm[r*40 + c8] = *(const short8*)&Bt[(size_t)(colBase+r)*Kpad + k0 + c8];
    }
    __syncthreads();
    short8 af[4], bfr[4];
    #pragma unroll
    for (int i=0;i<4;i++) af[i]  = *(short8*)&Asm[(wr + i*16 + lm)*40 + lk];
    #pragma unroll
    for (int j=0;j<4;j++) bfr[j] = *(short8*)&Bsm[(wc + j*16 + lm)*40 + lk];
    #pragma unroll
    for (int i=0;i<4;i++)
      #pragma unroll
      for (int j=0;j<4;j++)
        acc[i][j] = __builtin_amdgcn_mfma_f32_16x16x32_bf16(af[i], bfr[j], acc[i][j], 0,0,0);
    __syncthreads();
  }
  int cr = lane >> 4;
  #pragma unroll
  for (int i=0;i<4;i++) {
    #pragma unroll
    for (int j=0;j<4;j++) {
      int col = colBase + wc + j*16 + lm;
      if (col < Nout) {
        #pragma unroll
        for (int g=0; g<4; g++) {
          int row = rowBase + wr + i*16 + cr*4 + g;
          C[(size_t)row*ldc + col] = f2b(acc[i][j][g]);
        }
      }
    }
  }
}

// ---------------- per-node attention scalars ----------------

__global__ __launch_bounds__(256) void k_esed(const ushort* __restrict__ h,
                                              const float* __restrict__ asrc,
                                              const float* __restrict__ adst,
                                              float* __restrict__ es,
                                              float* __restrict__ ed,
                                              int dout, int hld) {
  int wid = threadIdx.x>>6, lane = threadIdx.x&63;
  int v = blockIdx.x*4 + wid;
  const ushort* hv = h + (size_t)v*hld;
  float s=0.f, d=0.f;
  for (int c=lane;c<dout;c+=64){ float x=b2f(hv[c]); s+=x*asrc[c]; d+=x*adst[c]; }
  #pragma unroll
  for (int o=32;o;o>>=1){ s+=__shfl_xor(s,o,64); d+=__shfl_xor(d,o,64); }
  if (lane==0){ es[v]=s; ed[v]=d; }
}

// ---------------- softmax + aggregation (one wave per node) ------
// XCD swizzle: dispatch round-robins blockIdx across 8 XCDs; map so all
// blocks of graph b land on XCD b%8 -> graph's h slab (640KB) stays in
// that XCD's 4MB L2 instead of being re-fetched by all 8.

__global__ __launch_bounds__(256) void k_aggregate(const ushort* __restrict__ h,
                                                   const float* __restrict__ es,
                                                   const float* __restrict__ ed,
                                                   const int* __restrict__ rowptr,
                                                   const int* __restrict__ csr_src,
                                                   const float* __restrict__ bias,
                                                   ushort* __restrict__ g,
                                                   int dout, int hld) {
  int wid = threadIdx.x>>6, lane = threadIdx.x&63;
  int bid = blockIdx.x;
  int xcd = bid & 7, slot = bid >> 3;
  int graph = xcd + ((slot >> 7) << 3);
  int v = graph*512 + (slot & 127)*4 + wid;
  int s0 = rowptr[v], e0 = rowptr[v+1];
  float edv = ed[v];
  float m = -__builtin_inff();
  for (int j = s0 + lane; j < e0; j += 64) {
    float e = es[csr_src[j]] + edv;
    e = e > 0.f ? e : 0.2f*e;
    m = fmaxf(m, e);
  }
  #pragma unroll
  for (int o=32;o;o>>=1) m = fmaxf(m, __shfl_xor(m,o,64));
  float den = 0.f;
  for (int j = s0 + lane; j < e0; j += 64) {
    float e = es[csr_src[j]] + edv;
    e = e > 0.f ? e : 0.2f*e;
    den += __expf(e - m);
  }
  #pragma unroll
  for (int o=32;o;o>>=1) den += __shfl_xor(den,o,64);
  float scale = 1.f/(den + 1e-16f);

  int nch = (dout + 7) >> 3;          // only real columns, not pad
  int ch0 = lane, ch1 = lane + 64;
  bool a0 = ch0 < nch, a1 = ch1 < nch;
  float acc0[8], acc1[8];
  #pragma unroll
  for (int q=0;q<8;q++){ acc0[q]=0.f; acc1[q]=0.f; }

  // software-pipelined gather: prefetch edge j+1 while FMA-ing edge j
  short8 cur0{}, cur1{}; float wcur = 0.f;
  if (s0 < e0) {
    int u = csr_src[s0];
    float e = es[u] + edv; e = e>0.f ? e : 0.2f*e;
    wcur = __expf(e - m) * scale;
    const ushort* hu = h + (size_t)u*hld;
    if (a0) cur0 = *(const short8*)&hu[ch0*8];
    if (a1) cur1 = *(const short8*)&hu[ch1*8];
  }
  for (int j = s0; j < e0; ++j) {
    short8 nxt0 = cur0, nxt1 = cur1; float wn = 0.f;
    if (j+1 < e0) {
      int u2 = csr_src[j+1];
      float e2 = es[u2] + edv; e2 = e2>0.f ? e2 : 0.2f*e2;
      wn = __expf(e2 - m) * scale;
      const ushort* hu2 = h + (size_t)u2*hld;
      if (a0) nxt0 = *(const short8*)&hu2[ch0*8];
      if (a1) nxt1 = *(const short8*)&hu2[ch1*8];
    }
    if (a0) {
      #pragma unroll
      for (int q=0;q<8;q++) acc0[q] += wcur * b2f((ushort)cur0[q]);
    }
    if (a1) {
      #pragma unroll
      for (int q=0;q<8;q++) acc1[q] += wcur * b2f((ushort)cur1[q]);
    }
    cur0 = nxt0; cur1 = nxt1; wcur = wn;
  }

  ushort* gv = g + (size_t)v*hld;
  if (a0) {
    short8 ov;
    #pragma unroll
    for (int q=0;q<8;q++) {
      int c = ch0*8+q;
      float val = (c < dout) ? acc0[q] + bias[c] : 0.f;
      ov[q] = (short)f2b(val);
    }
    *(short8*)&gv[ch0*8] = ov;
  }
  if (a1) {
    short8 ov;
    #pragma unroll
    for (int q=0;q<8;q++) {
      int c = ch1*8+q;
      float val = (c < dout) ? acc1[q] + bias[c] : 0.f;
      ov[q] = (short)f2b(val);
    }
    *(short8*)&gv[ch1*8] = ov;
  }
}

// ---------------- LN stats: grid (cols/64, B, 8 node-chunks) ----------------

__global__ __launch_bounds__(256) void k_ln_stats2(const ushort* __restrict__ g,
                                                   float* __restrict__ stats,
                                                   int ldg, int dout) {
  int b = blockIdx.y; int n0 = blockIdx.z*64;
  int lc = threadIdx.x & 63, r0 = threadIdx.x >> 6;
  int c = blockIdx.x*64 + lc;
  float s=0.f, q=0.f;
  if (c < dout) {
    #pragma unroll 4
    for (int i=0;i<16;i++) {
      int n = n0 + r0*16 + i;
      float x = b2f(g[(size_t)(b*N_+n)*ldg + c]);
      s+=x; q+=x*x;
    }
  }
  __shared__ float S[4][64], Q[4][64];
  S[r0][lc]=s; Q[r0][lc]=q; __syncthreads();
  if (r0==0 && c<dout) {
    atomicAdd(&stats[(size_t)b*dout+c],      S[0][lc]+S[1][lc]+S[2][lc]+S[3][lc]);
    atomicAdd(&stats[(size_t)(B_+b)*dout+c], Q[0][lc]+Q[1][lc]+Q[2][lc]+Q[3][lc]);
  }
}

// ---------------- LN apply + ReLU -> padded bf16 input (elementwise) ------

__global__ __launch_bounds__(256) void k_ln_apply2(const ushort* __restrict__ g,
                                                   const float* __restrict__ stats,
                                                   const float* __restrict__ sc,
                                                   const float* __restrict__ of,
                                                   ushort* __restrict__ xb,
                                                   int ldg, int dout, int Kpad) {
  int tid = threadIdx.x;
  int p = blockIdx.x*128 + (tid & 127);       // column-pair index
  int v = blockIdx.y*2 + (tid >> 7);
  int c0 = p*2;
  if (c0 >= Kpad) return;
  int b = v >> 9;
  uint gg = *(const uint*)&g[(size_t)v*ldg + c0];
  ushort r01[2] = {(ushort)(gg & 0xFFFFu), (ushort)(gg >> 16)};
  ushort ov[2];
  #pragma unroll
  for (int q=0;q<2;q++) {
    int c = c0+q;
    float y = 0.f;
    if (c < dout) {
      float mu  = stats[(size_t)b*dout+c] * (1.f/N_);
      float var = stats[(size_t)(B_+b)*dout+c]*(1.f/N_) - mu*mu;
      float x = b2f(r01[q]);
      y = (x-mu)*rsqrtf(var+1e-5f)*sc[c] + of[c];
      y = y>0.f ? y : 0.f;
    }
    ov[q] = f2b(y);
  }
  *(uint*)&xb[(size_t)v*Kpad + c0] = ((uint)ov[1]<<16) | ov[0];
}

// ---------------- reward: sum over nodes (8-way split + atomic) -----------

__global__ __launch_bounds__(256) void k_rsum(const ushort* __restrict__ g,
                                              float* __restrict__ out) {
  int b = blockIdx.y; int n0 = blockIdx.z*64;
  int lc = threadIdx.x & 63, r0 = threadIdx.x>>6;
  int c = blockIdx.x*64 + lc;
  float s = 0.f;
  if (c < FSS_) {
    #pragma unroll 4
    for (int i=0;i<16;i++) {
      int n = n0 + r0*16 + i;
      s += b2f(g[(size_t)(b*N_+n)*640 + c]);
    }
  }
  __shared__ float S[4][64];
  S[r0][lc]=s; __syncthreads();
  if (r0==0 && c<FSS_)
    atomicAdd(&out[b*FSS_+c], S[0][lc]+S[1][lc]+S[2][lc]+S[3][lc]);
}

// ---------------- ns_new assembly ----------------

__global__ __launch_bounds__(256) void k_output(const ushort* __restrict__ f,
                                                const float* __restrict__ ns,
                                                float* __restrict__ out) {
  int idx = blockIdx.x*256+threadIdx.x;
  if (idx >= B_*NSROW_) return;
  int b = idx / NSROW_; int j = idx - b*NSROW_;
  float v = (j < SLEFT_) ? b2f(f[(size_t)b*SLEFT_ + j]) : ns[(size_t)b*NSROW_ + j];
  out[OUT_R_ + idx] = v;
}

// ---------------- host driver ----------------

static void gat_layer(const ushort* xb, int Kpad, int dout, int hld, int Npadt,
                      const ushort* Wt, const float* as, const float* ad, const float* bias,
                      const float* sc, const float* of, ushort* xb_next, int Kpad_next,
                      ushort* h, ushort* g, float* es, float* ed, float* stats,
                      const int* rowptr, const int* csr_src, hipStream_t stream) {
  k_mfma_gemm<<<dim3(Npadt/128, BN_/128), 256, 0, stream>>>(xb, Wt, h, Kpad, hld, hld);
  k_esed<<<BN_/4, 256, 0, stream>>>(h, as, ad, es, ed, dout, hld);
  k_aggregate<<<BN_/4, 256, 0, stream>>>(h, es, ed, rowptr, csr_src, bias, g, dout, hld);
  if (sc) {
    hipMemsetAsync(stats, 0, (size_t)2*B_*dout*sizeof(float), stream);
    k_ln_stats2<<<dim3((dout+63)/64, B_, 8), 256, 0, stream>>>(g, stats, hld, dout);
    k_ln_apply2<<<dim3((Kpad_next+255)/256, BN_/2), 256, 0, stream>>>(g, stats, sc, of, xb_next, hld, dout, Kpad_next);
  }
}

extern "C" void kernel_launch(void* const* d_in, const int* in_sizes, int n_in,
                              void* d_out, int out_size, void* d_ws, size_t ws_size,
                              hipStream_t stream) {
  const float* ns = (const float*)d_in[0];
  const int*   a  = (const int*)d_in[1];

  const float *W[4], *As[4], *Ad[4], *Bb[4], *Sc[3], *Of[3];
  const float *rW[4], *rAs[4], *rAd[4], *rBb[4], *rSc[3], *rOf[3];
  int p = 2;
  for (int i=0;i<4;i++){
    W[i]=(const float*)d_in[p++]; As[i]=(const float*)d_in[p++];
    Ad[i]=(const float*)d_in[p++]; Bb[i]=(const float*)d_in[p++];
    if (i<3){ Sc[i]=(const float*)d_in[p++]; Of[i]=(const float*)d_in[p++]; }
  }
  for (int i=0;i<4;i++){
    rW[i]=(const float*)d_in[p++]; rAs[i]=(const float*)d_in[p++];
    rAd[i]=(const float*)d_in[p++]; rBb[i]=(const float*)d_in[p++];
    if (i<3){ rSc[i]=(const float*)d_in[p++]; rOf[i]=(const float*)d_in[p++]; }
  }

  char* w = (char*)d_ws;
  auto carve = [&](size_t bytes)->void* {
    void* r = (void*)w;
    w += (bytes + 255) & ~(size_t)255;
    return r;
  };
  ushort* xb   = (ushort*)carve((size_t)BN_*608*2);
  ushort* hbuf = (ushort*)carve((size_t)BN_*640*2);
  ushort* gbuf = (ushort*)carve((size_t)BN_*640*2);
  ushort* sabf = (ushort*)carve((size_t)BN_*64*2);
  float* es    = (float*)carve((size_t)BN_*4);
  float* ed    = (float*)carve((size_t)BN_*4);
  float* stats = (float*)carve((size_t)2*B_*FSS_*4);
  int* src_i   = (int*)carve((size_t)BE_*4);
  int* dst_i   = (int*)carve((size_t)BE_*4);
  int* cnt     = (int*)carve((size_t)BN_*4);
  int* rowptr  = (int*)carve((size_t)(BN_+1)*4);
  int* fill    = (int*)carve((size_t)BN_*4);
  int* csr_src = (int*)carve((size_t)BE_*4);
  ushort* rWt[4]; ushort* nWt[4];
  rWt[0] = (ushort*)carve((size_t)640*64*2);
  for (int i=1;i<4;i++) rWt[i] = (ushort*)carve((size_t)640*608*2);
  nWt[0] = (ushort*)carve((size_t)128*64*2);
  nWt[1] = (ushort*)carve((size_t)128*128*2);
  nWt[2] = (ushort*)carve((size_t)128*64*2);
  nWt[3] = (ushort*)carve((size_t)128*64*2);

  float* out = (float*)d_out;

  hipMemsetAsync(cnt,  0, (size_t)BN_*4, stream);
  hipMemsetAsync(fill, 0, (size_t)BN_*4, stream);
  hipMemsetAsync(out,  0, (size_t)OUT_R_*4, stream);

  k_indices<<<(BE_+255)/256, 256, 0, stream>>>(ns, src_i, dst_i, cnt);
  k_scan<<<1, 1024, 0, stream>>>(cnt, rowptr);
  k_scatter<<<(BE_+255)/256, 256, 0, stream>>>(src_i, dst_i, rowptr, fill, csr_src);
  k_sa<<<(BN_*64+255)/256, 256, 0, stream>>>(ns, a, sabf);

  k_wt<<<(64*640+255)/256, 256, 0, stream>>>(rW[0], rWt[0], 33, 601, 64, 640);
  for (int i=1;i<4;i++)
    k_wt<<<(608*640+255)/256, 256, 0, stream>>>(rW[i], rWt[i], 601, 601, 608, 640);
  k_wt<<<(64*128+255)/256, 256, 0, stream>>>(W[0], nWt[0], 33, 128, 64, 128);
  k_wt<<<(128*128+255)/256, 256, 0, stream>>>(W[1], nWt[1], 128, 64, 128, 128);
  k_wt<<<(64*128+255)/256, 256, 0, stream>>>(W[2], nWt[2], 64, 64, 64, 128);
  k_wt<<<(64*128+255)/256, 256, 0, stream>>>(W[3], nWt[3], 64, 32, 64, 128);

  // reward head
  gat_layer(sabf, 64,  FSS_, 640, 640, rWt[0], rAs[0],rAd[0],rBb[0], rSc[0],rOf[0], xb, 608, hbuf, gbuf, es, ed, stats, rowptr, csr_src, stream);
  gat_layer(xb,   608, FSS_, 640, 640, rWt[1], rAs[1],rAd[1],rBb[1], rSc[1],rOf[1], xb, 608, hbuf, gbuf, es, ed, stats, rowptr, csr_src, stream);
  gat_layer(xb,   608, FSS_, 640, 640, rWt[2], rAs[2],rAd[2],rBb[2], rSc[2],rOf[2], xb, 608, hbuf, gbuf, es, ed, stats, rowptr, csr_src, stream);
  gat_layer(xb,   608, FSS_, 640, 640, rWt[3], rAs[3],rAd[3],rBb[3], nullptr,nullptr, nullptr, 0, hbuf, gbuf, es, ed, stats, rowptr, csr_src, stream);
  k_rsum<<<dim3(10, B_, 8), 256, 0, stream>>>(gbuf, out);

  // next-state head
  gat_layer(sabf, 64,  128, 128, 128, nWt[0], As[0],Ad[0],Bb[0], Sc[0],Of[0], xb, 128, hbuf, gbuf, es, ed, stats, rowptr, csr_src, stream);
  gat_layer(xb,   128, 64,  64,  128, nWt[1], As[1],Ad[1],Bb[1], Sc[1],Of[1], xb, 64,  hbuf, gbuf, es, ed, stats, rowptr, csr_src, stream);
  gat_layer(xb,   64,  64,  64,  128, nWt[2], As[2],Ad[2],Bb[2], Sc[2],Of[2], xb, 64,  hbuf, gbuf, es, ed, stats, rowptr, csr_src, stream);
  gat_layer(xb,   64,  32,  32,  128, nWt[3], As[3],Ad[3],Bb[3], nullptr,nullptr, nullptr, 0, hbuf, gbuf, es, ed, stats, rowptr, csr_src, stream);
  k_output<<<(B_*NSROW_+255)/256, 256, 0, stream>>>(gbuf, ns, out);
}